// Round 1
// baseline (380.153 us; speedup 1.0000x reference)
//
#include <hip/hip_runtime.h>
#include <math.h>

typedef float v2f __attribute__((ext_vector_type(2)));

__device__ __forceinline__ v2f v2fma(v2f a, v2f b, v2f c) {
    return __builtin_elementwise_fma(a, b, c);
}

constexpr int S_LEN  = 4096;
constexpr int GROUPS = S_LEN / 4;     // 1024 float4 groups per row
constexpr int PF     = 8;             // prefetch depth in groups (32 steps ahead)
constexpr int OUTER  = GROUPS / PF;   // 128

// One thread = one chain. 8192 chains -> 128 waves -> ~1 wave/SIMD on 128 CUs.
// Recurrence (alpha,beta runtime scalars; ca=cos(a/2) etc.):
//   a_t = [ca*c, -sa*s, ca*s, sa*c],  c=cos(atan(x)/2), s=sin(atan(x)/2)
//   g <- rn * (rz g) + a_t ;  rn = rsqrt(|g|^2)   (normalization deferred/folded)
// Trig-free: r=rsqrt(1+x^2); u=2+2r; v=rsqrt(u); c=0.5*u*v; s=x*r*v.
__global__ __launch_bounds__(64)
void qrnn_kernel(const float* __restrict__ x,
                 const float* __restrict__ alpha_p,
                 const float* __restrict__ beta_p,
                 float* __restrict__ out, int B)
{
    int b = blockIdx.x * 64 + threadIdx.x;
    if (b >= B) return;

    float alpha = alpha_p[0], beta = beta_p[0];
    float sa, ca, sb, cb;
    sincosf(0.5f * alpha, &sa, &ca);
    sincosf(0.5f * beta,  &sb, &cb);

    const float4* __restrict__ xrow =
        reinterpret_cast<const float4*>(x) + (size_t)b * GROUPS;

    // register prefetch ring: 8 x float4 = 32 steps in flight
    float4 buf[PF];
#pragma unroll
    for (int i = 0; i < PF; ++i) buf[i] = xrow[i];

    v2f g01 = {0.f, 0.f}, g23 = {0.f, 0.f};
    float rn = 1.0f;

    const v2f cbv  = {cb, cb};
    const v2f sb01 = {-sb, sb};   // q0 = cb*g0 - sb*g1 ; q1 = cb*g1 + sb*g0
    const v2f sb23 = {sb, -sb};   // q2 = cb*g2 + sb*g3 ; q3 = cb*g3 - sb*g2
    const v2f ea01 = {ca, -sa};   // addend (ca*c, -sa*s)
    const v2f ea23 = {ca, sa};    // addend (ca*s,  sa*c)

    auto step = [&](float xt) {
        float t = __builtin_fmaf(xt, xt, 1.0f);
        float r = __frsqrt_rn(t);                 // cos(phi)
        float u = __builtin_fmaf(2.0f, r, 2.0f);  // 2+2r
        float v = __frsqrt_rn(u);
        v2f hx;
        hx.x = 0.5f * u;                          // c = 0.5*u*v
        hx.y = xt * r;                            // s = x*r*v
        v2f vv = {v, v};
        v2f cs  = hx * vv;
        v2f a01 = cs * ea01;
        v2f a23 = cs.yx * ea23;
        v2f q01 = v2fma(g01.yx, sb01, g01 * cbv); // rz * g (deferred scale)
        v2f q23 = v2fma(g23.yx, sb23, g23 * cbv);
        v2f rnv = {rn, rn};
        g01 = v2fma(rnv, q01, a01);
        g23 = v2fma(rnv, q23, a23);
        v2f p = v2fma(g23, g23, g01 * g01);
        float n = p.x + p.y;
        rn = __frsqrt_rn(n);
    };

    auto group4 = [&](const float4& xv) {
        step(xv.x); step(xv.y); step(xv.z); step(xv.w);
    };

    // main loop: consume buf[i], immediately re-issue load 8 groups (32 steps) ahead
    for (int j = 0; j < OUTER - 1; ++j) {
#pragma unroll
        for (int i = 0; i < PF; ++i) {
            float4 xv = buf[i];
            buf[i] = xrow[(j + 1) * PF + i];
            group4(xv);
        }
    }
    // peeled last 8 groups: no prefetch
#pragma unroll
    for (int i = 0; i < PF; ++i) group4(buf[i]);

    // z = (h0^2+h1^2 - h2^2 - h3^2) with h = g/|g|  ->  (s01-s23)/(s01+s23)
    float s01 = g01.x * g01.x + g01.y * g01.y;
    float s23 = g23.x * g23.x + g23.y * g23.y;
    out[b] = (s01 - s23) / (s01 + s23);
}

extern "C" void kernel_launch(void* const* d_in, const int* in_sizes, int n_in,
                              void* d_out, int out_size, void* d_ws, size_t ws_size,
                              hipStream_t stream) {
    const float* x       = (const float*)d_in[0];
    const float* alpha_p = (const float*)d_in[1];
    const float* beta_p  = (const float*)d_in[2];
    float* out = (float*)d_out;
    int B = out_size;                  // 8192
    int grid = (B + 63) / 64;          // 128 blocks x 64 threads = 1 wave/block
    qrnn_kernel<<<grid, 64, 0, stream>>>(x, alpha_p, beta_p, out, B);
}

// Round 2
// 297.726 us; speedup vs baseline: 1.2769x; 1.2769x over previous
//
#include <hip/hip_runtime.h>
#include <math.h>

constexpr int S_LEN  = 4096;
constexpr int GROUPS = S_LEN / 4;     // 1024 float4 groups per chain
constexpr int PF     = 8;             // prefetch depth in groups (32 steps ahead)
constexpr int OUTER  = GROUPS / PF;   // 128

// Cross-lane pair swap (lane 2k <-> 2k+1) via DPP quad_perm [1,0,3,2] — pure VALU.
__device__ __forceinline__ float pair_swap(float v) {
    int j = __builtin_amdgcn_mov_dpp(__builtin_bit_cast(int, v), 0xB1, 0xF, 0xF, true);
    return __builtin_bit_cast(float, j);
}

// 2 lanes per chain: parity 0 holds (h0,h1), parity 1 holds (h2,h3).
// Rz is block-diagonal on those pairs -> rotation stays in-lane.
// Deferred normalization: g unnormalized, rn = 1/|g| folded into next step.
// Norm identity (exact): |g'|^2 = 2 + 2*rn*<q,a>  since |rn*q|=1 and |a|=1.
// Trig-free embed: r=rsqrt(1+x^2)=cos(phi); c=0.5*(2+2r)*v, s=x*r*v, v=rsqrt(2+2r).
__global__ __launch_bounds__(64)
void qrnn_kernel(const float* __restrict__ x,
                 const float* __restrict__ alpha_p,
                 const float* __restrict__ beta_p,
                 float* __restrict__ out, int B)
{
    const int lane  = threadIdx.x & 63;
    const int par   = lane & 1;
    const int chain = blockIdx.x * 32 + (lane >> 1);
    if (chain >= B) return;

    float sa, ca, sb, cb;
    sincosf(0.5f * alpha_p[0], &sa, &ca);
    sincosf(0.5f * beta_p[0],  &sb, &cb);

    // Rz pair rotation: q = cb*g + (svx,svy)*g.yx
    //   parity 0: q0 = cb*g0 - sb*g1 ; q1 = cb*g1 + sb*g0
    //   parity 1: q2 = cb*g2 + sb*g3 ; q3 = cb*g3 - sb*g2
    const float svx = par ?  sb : -sb;
    const float svy = par ? -sb :  sb;
    // addend a = (e1*v, e2*v);  e_i = fma(Ai,r,Ai) + Bi*xr
    //   parity 0: a = (ca*c, -sa*s)  -> A1=ca, B1=0,  A2=0,  B2=-sa
    //   parity 1: a = (ca*s,  sa*c)  -> A1=0,  B1=ca, A2=sa, B2=0
    const float A1 = par ? 0.0f : ca;
    const float B1 = par ? ca   : 0.0f;
    const float A2 = par ? sa   : 0.0f;
    const float B2 = par ? 0.0f : -sa;

    const float4* __restrict__ xrow =
        reinterpret_cast<const float4*>(x) + (size_t)chain * GROUPS;

    float4 buf[PF];
#pragma unroll
    for (int i = 0; i < PF; ++i) buf[i] = xrow[i];

    float gx = 0.f, gy = 0.f, rn = 1.f;

    auto embed = [&](float xt, float& ax, float& ay) {
        float t  = __builtin_fmaf(xt, xt, 1.0f);
        float r  = __frsqrt_rn(t);                  // cos(phi)
        float u  = __builtin_fmaf(2.0f, r, 2.0f);   // 2+2r
        float v  = __frsqrt_rn(u);
        float xr = xt * r;                          // sin(phi)
        ax = __builtin_fmaf(B1, xr, __builtin_fmaf(A1, r, A1)) * v;
        ay = __builtin_fmaf(B2, xr, __builtin_fmaf(A2, r, A2)) * v;
    };

    auto step = [&](float xt) {
        float ax, ay; embed(xt, ax, ay);
        float qx = __builtin_fmaf(svx, gy, cb * gx);
        float qy = __builtin_fmaf(svy, gx, cb * gy);
        float d  = __builtin_fmaf(qy, ay, qx * ax);     // lane-partial <q,a>
        gx = __builtin_fmaf(rn, qx, ax);
        gy = __builtin_fmaf(rn, qy, ay);
        float dsum = d + pair_swap(d);                  // full <q,a>
        float rn2  = rn + rn;
        rn = __frsqrt_rn(__builtin_fmaf(rn2, dsum, 2.0f));
    };

    auto group4 = [&](const float4& xv) {
        step(xv.x); step(xv.y); step(xv.z); step(xv.w);
    };

    // ---- group 0 peeled: element 0 is embed-only (hidden0 = 0 -> g = a, |a|=1) ----
    {
        float4 xv = buf[0];
        buf[0] = xrow[PF];
        float ax, ay; embed(xv.x, ax, ay);
        gx = ax; gy = ay; rn = 1.0f;
        step(xv.y); step(xv.z); step(xv.w);
#pragma unroll
        for (int i = 1; i < PF; ++i) {
            float4 xv2 = buf[i];
            buf[i] = xrow[PF + i];
            group4(xv2);
        }
    }
    // ---- main ring: consume buf[i], refill 8 groups (32 steps) ahead ----
    for (int j = 1; j < OUTER - 1; ++j) {
#pragma unroll
        for (int i = 0; i < PF; ++i) {
            float4 xv = buf[i];
            buf[i] = xrow[(j + 1) * PF + i];
            group4(xv);
        }
    }
    // ---- tail: last 8 groups, no refill ----
#pragma unroll
    for (int i = 0; i < PF; ++i) group4(buf[i]);

    // z = (s01 - s23)/(s01 + s23); parity-0 lane holds s01, partner holds s23
    float ss = __builtin_fmaf(gy, gy, gx * gx);
    float so = pair_swap(ss);
    if (par == 0) out[chain] = (ss - so) / (ss + so);
}

extern "C" void kernel_launch(void* const* d_in, const int* in_sizes, int n_in,
                              void* d_out, int out_size, void* d_ws, size_t ws_size,
                              hipStream_t stream) {
    const float* x       = (const float*)d_in[0];
    const float* alpha_p = (const float*)d_in[1];
    const float* beta_p  = (const float*)d_in[2];
    float* out = (float*)d_out;
    int B = out_size;                       // 8192 chains
    int grid = (B + 31) / 32;               // 32 chains per 64-thread block -> 256 blocks
    qrnn_kernel<<<grid, 64, 0, stream>>>(x, alpha_p, beta_p, out, B);
}

// Round 3
// 256.522 us; speedup vs baseline: 1.4819x; 1.1606x over previous
//
#include <hip/hip_runtime.h>
#include <math.h>

constexpr int S_LEN = 4096;
constexpr int W     = 32;            // steps per window
constexpr int NW    = S_LEN / W;     // 128 windows
constexpr int CPB   = 32;            // chains per block

// lane 2k <-> 2k+1 swap via DPP quad_perm [1,0,3,2]
__device__ __forceinline__ float pair_swap(float v) {
    int j = __builtin_amdgcn_mov_dpp(__builtin_bit_cast(int, v), 0xB1, 0xF, 0xF, true);
    return __builtin_bit_cast(float, j);
}

// Quaternion reformulation:
//   h' = N(L e_t + h R);  L = ca + sa k,  R = cb + sb i,  e_t = c + s j
//   u_t = h_t R^{-t}  =>  u_{t+1} = N(u_t + b_t),  b_t = L e_t R^{-(t+1)}
//   measurement w^2+x^2-y^2-z^2 invariant under right-mult by R^S -> use u directly.
// With C=cos((t+1)b/2), S=sin((t+1)b/2), e1=cC,e2=cS,e3=sC,e4=sS:
//   bw =  ca e1 - sa e4 ; bx = -(ca e2 + sa e3) ; by = ca e3 - sa e2 ; bz = sa e1 + ca e4
// Consumer recurrence (deferred norm, g unnormalized, rn = 1/|g|):
//   g' = rn g + b ;  |g'|^2 = 2 + 2 rn <g,b>   (both u and b unit)
__global__ __launch_bounds__(192)
void qrnn_kernel(const float* __restrict__ x,
                 const float* __restrict__ alpha_p,
                 const float* __restrict__ beta_p,
                 float* __restrict__ out)
{
    __shared__ float2 cstab[S_LEN];                    // (C_t, S_t)  32 KB
    __shared__ float2 bbuf[2 * W * 2 * CPB];           // [sel][s][par][chain] 32 KB

    const int tid = threadIdx.x;

    // ---- cooperative (C,S) table init, f64 angle reduction ----
    {
        const double hb = 0.5 * (double)beta_p[0];
        const double twopi = 6.283185307179586476925287;
        const double inv2pi = 0.15915494309189533576888;
        for (int t = tid; t < S_LEN; t += 192) {
            double ang = (double)(t + 1) * hb;
            ang -= floor(ang * inv2pi) * twopi;
            float fa = (float)ang;
            float sv, cv;
            __sincosf(fa, &sv, &cv);
            cstab[t] = make_float2(cv, sv);
        }
    }
    __syncthreads();

    const int wave = tid >> 6;
    const int lane = tid & 63;

    if (wave != 0) {
        // ================= PRODUCER (waves 1,2) =================
        float sa, ca;
        __sincosf(0.5f * alpha_p[0], &sa, &ca);

        const int plane = tid - 64;          // 0..127
        const int c     = plane & 31;        // chain within block
        const int half  = plane >> 5;        // 0..3 -> 8 steps each
        const float4* __restrict__ xrow =
            reinterpret_cast<const float4*>(x) +
            (size_t)(blockIdx.x * CPB + c) * (S_LEN / 4);

        auto fill = [&](int w, const float4& c0, const float4& c1) {
            const int sel = w & 1;
            const int wb  = w * W;
            float xv[8] = {c0.x, c0.y, c0.z, c0.w, c1.x, c1.y, c1.z, c1.w};
#pragma unroll
            for (int i = 0; i < 8; ++i) {
                int s = half * 8 + i;
                float2 cs = cstab[wb + s];
                float xt = xv[i];
                float t1 = __builtin_fmaf(xt, xt, 1.0f);
                float r  = __frsqrt_rn(t1);                  // cos(phi)
                float wv = __builtin_fmaf(0.5f, r, 0.5f);    // c^2
                float v  = __frsqrt_rn(wv);
                float cc = wv * v;                           // c = sqrt(wv)
                float xr = xt * r;                           // sin(phi)
                float ss = xr * (0.5f * v);                  // s = sin(phi)/(2c)
                float e1 = cc * cs.x, e2 = cc * cs.y;
                float e3 = ss * cs.x, e4 = ss * cs.y;
                float bw =  __builtin_fmaf(ca, e1, -sa * e4);
                float bx = -__builtin_fmaf(ca, e2,  sa * e3);
                float by =  __builtin_fmaf(ca, e3, -sa * e2);
                float bz =  __builtin_fmaf(sa, e1,  ca * e4);
                int base = ((sel * W + s) * 2) * CPB + c;
                bbuf[base]       = make_float2(bw, bx);      // parity 0
                bbuf[base + CPB] = make_float2(by, bz);      // parity 1
            }
        };

        // window 0
        float4 a0 = xrow[half * 2];
        float4 a1 = xrow[half * 2 + 1];
        fill(0, a0, a1);
        float4 n0 = xrow[8 + half * 2];
        float4 n1 = xrow[8 + half * 2 + 1];
        __syncthreads();

        for (int w = 0; w < NW; ++w) {
            if (w + 1 < NW) {
                float4 b0 = n0, b1 = n1;
                if (w + 2 < NW) {
                    n0 = xrow[(w + 2) * 8 + half * 2];
                    n1 = xrow[(w + 2) * 8 + half * 2 + 1];
                }
                fill(w + 1, b0, b1);
            }
            __syncthreads();
        }
    } else {
        // ================= CONSUMER (wave 0) =================
        const int c = lane >> 1;             // chain within block
        const int p = lane & 1;              // parity: 0 -> (w,x), 1 -> (y,z)
        const int pbase = p * CPB + c;       // + (sel*W+s)*2*CPB

        float gx = 0.f, gy = 0.f, rn = 1.f;

        __syncthreads();   // matches producer's post-fill(0) barrier

        for (int w = 0; w < NW; ++w) {
            const int sel  = w & 1;
            const int woff = sel * W * 2 * CPB + pbase;

            auto step = [&](int s) {
                float2 b = bbuf[woff + s * 2 * CPB];
                float dp   = __builtin_fmaf(gy, b.y, gx * b.x);   // lane-partial <g,b>
                float dsum = dp + pair_swap(dp);
                float m    = __builtin_fmaf(rn + rn, dsum, 2.0f); // |g'|^2 pre-scale
                gx = __builtin_fmaf(rn, gx, b.x);
                gy = __builtin_fmaf(rn, gy, b.y);
                rn = __frsqrt_rn(m);
            };

            if (w == 0) {
                // peel t=0: u_1 = b_0 exactly (|b|=1)
                float2 b0 = bbuf[woff];
                gx = b0.x; gy = b0.y; rn = 1.0f;
#pragma unroll
                for (int s = 1; s < W; ++s) step(s);
            } else {
#pragma unroll
                for (int s = 0; s < W; ++s) step(s);
            }
            __syncthreads();
        }

        // z = (u0^2+u1^2 - u2^2 - u3^2); ratio cancels |g|
        float ss = __builtin_fmaf(gy, gy, gx * gx);
        float so = pair_swap(ss);
        if (p == 0) out[blockIdx.x * CPB + c] = (ss - so) / (ss + so);
    }
}

extern "C" void kernel_launch(void* const* d_in, const int* in_sizes, int n_in,
                              void* d_out, int out_size, void* d_ws, size_t ws_size,
                              hipStream_t stream) {
    const float* x       = (const float*)d_in[0];
    const float* alpha_p = (const float*)d_in[1];
    const float* beta_p  = (const float*)d_in[2];
    float* out = (float*)d_out;
    int grid = out_size / CPB;               // 8192/32 = 256 blocks, 1 per CU
    qrnn_kernel<<<grid, 192, 0, stream>>>(x, alpha_p, beta_p, out);
}